// Round 16
// baseline (1239.097 us; speedup 1.0000x reference)
//
#include <hip/hip_runtime.h>
#include <cstdint>

typedef short short8 __attribute__((ext_vector_type(8)));
typedef float f32x4 __attribute__((ext_vector_type(4)));

#define LDS_AS3(p) ((__attribute__((address_space(3))) unsigned*)(p))
#define GLB_AS1(p) ((const __attribute__((address_space(1))) unsigned*)(p))

// fp32 -> bf16 (round-to-nearest-even), two packed into a u32
__device__ inline unsigned bfpack(float a, float b) {
    union { float f; unsigned u; } ua, ub;
    ua.f = a; ub.f = b;
    unsigned lo = (ua.u + 0x7FFFu + ((ua.u >> 16) & 1u)) >> 16;
    unsigned hi = (ub.u + 0x7FFFu + ((ub.u >> 16) & 1u)) & 0xFFFF0000u;
    return lo | hi;
}
__device__ inline unsigned short bf16of(float a) { return (unsigned short)bfpack(a, 0.0f); }
__device__ inline float bf2f(unsigned short s) {
    union { unsigned u; float f; } x; x.u = (unsigned)s << 16; return x.f;
}

constexpr int E1S = 2308;   // EXT1 row stride (shorts); col = n-576 (8B-aligned runs)

// ---------------- prepass: convert X to bf16 (same [.,448,512] layout) ------
__global__ __launch_bounds__(256)
void cvt_x(const float* __restrict__ X, unsigned short* __restrict__ XB)
{
    const int g = blockIdx.x * 256 + threadIdx.x;
    const float4 v0 = *(const float4*)(X + (size_t)g * 8);
    const float4 v1 = *(const float4*)(X + (size_t)g * 8 + 4);
    uint4 u;
    u.x = bfpack(v0.x, v0.y); u.y = bfpack(v0.z, v0.w);
    u.z = bfpack(v1.x, v1.y); u.w = bfpack(v1.z, v1.w);
    *(uint4*)(XB + (size_t)g * 8) = u;
}

// ------------- prepass: convert + transpose W[512][N] -> WT[N][512] bf16 ----
template <int N>
__global__ __launch_bounds__(256)
void cvt_w(const float* __restrict__ W, unsigned short* __restrict__ WT)
{
    const int g = blockIdx.x * 256 + threadIdx.x;
    if (g >= N * 64) return;
    const int n = g % N, d8 = g / N;
    const float* p = W + (size_t)d8 * 8 * N + n;
    uint4 u;
    u.x = bfpack(p[0],             p[(size_t)N]);
    u.y = bfpack(p[2 * (size_t)N], p[3 * (size_t)N]);
    u.z = bfpack(p[4 * (size_t)N], p[5 * (size_t)N]);
    u.w = bfpack(p[6 * (size_t)N], p[7 * (size_t)N]);
    *(uint4*)(WT + (size_t)n * 512 + d8 * 8) = u;
}

// ---- 128x256 GEMM, 512 thr (8 waves 2Mx4N), BK=32 dbuf, 2 blocks/CU --------
// R12's phases verbatim (proven 294us) re-packaged so TWO independent blocks
// fit per CU (LDS <= 66.5KB, VGPR <= 128): block A's K-loop overlaps block
// B's epilogue. R14 BUG FIX: MODE1/MODE2 grids must use M/128 m-tiles
// (128*12, 256*5) -- R14 launched half the rows.
template <int MODE>
__global__ __launch_bounds__(512, 4)
void gemm_big(const unsigned short* __restrict__ XB,
              const unsigned short* __restrict__ WT,
              const float* __restrict__ BIAS, float* __restrict__ Y,
              const unsigned short* __restrict__ EXTI,
              unsigned short* __restrict__ EXTO)
{
    constexpr int K_L  = (MODE == 0) ? 64 : (MODE == 1) ? 128 : 256;
    constexpr int LOGK = (MODE == 0) ? 6  : (MODE == 1) ? 7   : 8;
    constexpr int N    = (MODE == 0) ? 1180 : (MODE == 1) ? 2881 : 1153;
    constexpr int XOFF = (MODE == 0) ? 0 : (MODE == 1) ? 64 : 192;
    constexpr int NT   = (N + 255) / 256;
    constexpr int RPP   = (MODE == 2) ? 32 : 64;      // epilogue rows/pass
    constexpr int NPASS = 128 / RPP;
    constexpr int RPW   = RPP / 8;
    constexpr int SMEM  = (MODE == 2) ? 51200 : 66560; // max(K-loop 48K, epi)

    __shared__ __align__(16) char smem[SMEM];
    unsigned short* lAp = (unsigned short*)smem;      // [2][128*32] = 16KB
    unsigned short* lBp = lAp + 8192;                  // [2][256*32] = 32KB

    const int t    = threadIdx.x;            // 0..511
    const int lane = t & 63;
    const int wv   = t >> 6;                 // 0..7
    const int wr   = wv >> 2;                // m half 0..1
    const int wc   = wv & 3;                 // n quarter 0..3
    const int kq   = lane >> 4;
    const int lr16 = lane & 15;

    // bijective XCD-chunk swizzle (grids divisible by 8); N-minor order
    const int cpx = (int)gridDim.x >> 3;
    const int wg  = (blockIdx.x & 7) * cpx + (blockIdx.x >> 3);
    const int nt  = wg % NT;
    const int mt  = wg / NT;
    const int m0  = mt * 128;
    const int n0  = nt * 256;

    // stage one BK=32 tile: A 512 chunks + B 1024 chunks, 3 gload_lds/thread.
    // physical slot p holds logical k-slot p^((row>>1)&3) (proven R1 swizzle).
    auto stage = [&](int buf, int kt) {
        {   // A: 128 rows x 4 slots
            const int c   = t;
            const int row = c >> 2, p = c & 3, l = p ^ ((row >> 1) & 3);
            const int m   = m0 + row;
            const int b   = m >> LOGK, kd = m & (K_L - 1);
            const unsigned short* gp =
                XB + ((size_t)(b * 448 + XOFF + kd) << 9) + kt * 32 + l * 8;
            __builtin_amdgcn_global_load_lds(GLB_AS1(gp),
                LDS_AS3(lAp + buf * 4096 + c * 8), 16, 0, 0);
        }
        #pragma unroll
        for (int i = 0; i < 2; ++i) {   // B: 256 rows x 4 slots
            const int c   = i * 512 + t;
            const int row = c >> 2, p = c & 3, l = p ^ ((row >> 1) & 3);
            int gc = n0 + row; if (gc > N - 1) gc = N - 1;
            const unsigned short* gp = WT + (size_t)gc * 512 + kt * 32 + l * 8;
            __builtin_amdgcn_global_load_lds(GLB_AS1(gp),
                LDS_AS3(lBp + buf * 8192 + c * 8), 16, 0, 0);
        }
    };

    f32x4 acc[4][4] = {};

    // ---- K loop: 16 tiles of 32 --------------------------------------------
    stage(0, 0);
    __syncthreads();
    #pragma unroll 1
    for (int kt = 0; kt < 16; ++kt) {
        const int buf = kt & 1;
        if (kt < 15) stage(buf ^ 1, kt + 1);
        short8 af[4], bf[4];
        #pragma unroll
        for (int mi = 0; mi < 4; ++mi) {
            const int row = wr * 64 + mi * 16 + lr16;
            af[mi] = *(const short8*)(lAp + buf * 4096 + row * 32 + ((kq ^ ((row >> 1) & 3)) * 8));
        }
        #pragma unroll
        for (int ni = 0; ni < 4; ++ni) {
            const int row = wc * 64 + ni * 16 + lr16;
            bf[ni] = *(const short8*)(lBp + buf * 8192 + row * 32 + ((kq ^ ((row >> 1) & 3)) * 8));
        }
        __builtin_amdgcn_s_setprio(1);
        #pragma unroll
        for (int mi = 0; mi < 4; ++mi)
            #pragma unroll
            for (int ni = 0; ni < 4; ++ni)
                acc[mi][ni] = __builtin_amdgcn_mfma_f32_16x16x32_bf16(
                    af[mi], bf[ni], acc[mi][ni], 0, 0, 0);
        __builtin_amdgcn_s_setprio(0);
        __syncthreads();
    }

    // ================= epilogue (R12 structure, NPASS passes) ==============
    float* LDSf = (float*)smem;                        // [RPP][260]
    unsigned short* panel = (unsigned short*)(smem + 33280);  // MODE2 only

    const int cls = (MODE == 0) ? ((n0 == 0 || n0 + 255 >= N) ? 2 : 1)
                  : (MODE == 1) ? ((n0 + 255 < 576) ? 0 : (n0 <= 576) ? 2
                                   : (n0 + 255 < N) ? 1 : 2)
                  :               ((n0 + 255 < 1152) ? 0 : 2);

    int row_lo = 0;
    #pragma unroll 1
    for (int h = 0; h < NPASS; ++h) {
        if (h) __syncthreads();
        if constexpr (MODE != 2) {
            if (wr == h) {
                #pragma unroll
                for (int mi = 0; mi < 4; ++mi)
                    #pragma unroll
                    for (int ni = 0; ni < 4; ++ni)
                        #pragma unroll
                        for (int r = 0; r < 4; ++r)
                            LDSf[(mi * 16 + kq * 4 + r) * 260 + wc * 64 + ni * 16 + lr16]
                                = acc[mi][ni][r];
            }
        } else {
            if (wr == (h >> 1)) {
                #pragma unroll
                for (int mi2 = 0; mi2 < 2; ++mi2)
                    #pragma unroll
                    for (int ni = 0; ni < 4; ++ni)
                        #pragma unroll
                        for (int r = 0; r < 4; ++r)
                            LDSf[(mi2 * 16 + kq * 4 + r) * 260 + wc * 64 + ni * 16 + lr16]
                                = acc[(h & 1) * 2 + mi2][ni][r];
            }
            // ---- load E1 panel (coalesced); kd range = (mt&1)*128+h*32 ..+32
            row_lo = n0 / 9;
            const int ntop  = (n0 + 256 <= 1152) ? (n0 + 255) : 1151;
            const int nrows = ntop / 9 - row_lo + 1;
            const int col0  = (mt & 1) * 1152 + h * 288;
            const int bB    = mt >> 1;
            for (int t2 = t; t2 < nrows * 73; t2 += 512) {
                const int rr2 = t2 / 73, cc = t2 % 73;
                const uint2 v = *(const uint2*)(EXTI +
                    ((size_t)(bB * 128 + row_lo + rr2)) * E1S + col0 + cc * 4);
                *(uint2*)(panel + rr2 * 296 + cc * 4) = v;
            }
        }
        __syncthreads();

        #pragma unroll 1
        for (int rr = 0; rr < RPW; ++rr) {
            const int ml = wv * RPW + rr;
            const int m  = m0 + h * RPP + ml;
            const int b  = m >> LOGK;
            const int kd = m & (K_L - 1);
            const int nb = n0 + lane * 4;
            const float4 v4 = *(const float4*)&LDSf[ml * 260 + lane * 4];
            float* yb = Y + (size_t)b * 370816;

            if (cls == 0) {
                const float4 b4 = *(const float4*)(BIAS + nb);
                float e[4];
                if constexpr (MODE == 1) {
                    #pragma unroll
                    for (int i = 0; i < 4; ++i) {
                        const int n = nb + i;
                        e[i] = bf2f(EXTI[((size_t)(b * 64 + n / 9)) * 1152 + kd * 9 + n % 9]);
                    }
                    float4 o;
                    o.x = 0.5f * (v4.x + b4.x + e[0]); o.y = 0.5f * (v4.y + b4.y + e[1]);
                    o.z = 0.5f * (v4.z + b4.z + e[2]); o.w = 0.5f * (v4.w + b4.w + e[3]);
                    *(float4*)(yb + 1792 + kd * 576 + nb) = o;
                } else {
                    #pragma unroll
                    for (int i = 0; i < 4; ++i) {
                        const int n = nb + i;
                        e[i] = bf2f(panel[(n / 9 - row_lo) * 296 + ml * 9 + n % 9 + 1]);
                    }
                    float4 o;
                    o.x = v4.x + b4.x + e[0]; o.y = v4.y + b4.y + e[1];
                    o.z = v4.z + b4.z + e[2]; o.w = v4.w + b4.w + e[3];
                    *(float4*)(yb + 75648 + kd * 1152 + nb) = o;
                }
                if (MODE == 2 && n0 + 256 > 1152 && lane == 32)
                    yb[370560 + kd] = LDSf[ml * 260 + 128] + BIAS[1152];
            } else if (cls == 1) {
                const float4 b4 = *(const float4*)(BIAS + nb);
                uint2 u;
                u.x = bfpack(v4.x + b4.x, v4.y + b4.y);
                u.y = bfpack(v4.z + b4.z, v4.w + b4.w);
                if constexpr (MODE == 0)
                    *(uint2*)(EXTO + ((size_t)(b * 64 + kd)) * 1152 + (nb - 28)) = u;
                else
                    *(uint2*)(EXTO + ((size_t)(b * 128 + kd)) * E1S + (nb - 576)) = u;
            } else {
                #pragma unroll
                for (int i = 0; i < 4; ++i) {
                    const int n = nb + i;
                    if (n >= N) continue;
                    const float v = ((const float*)&v4)[i] + BIAS[n];
                    if constexpr (MODE == 0) {
                        if (n < 27)       yb[kd * 27 + n] = v;
                        else if (n == 27) yb[1728 + kd]   = v;
                        else EXTO[((size_t)(b * 64 + kd)) * 1152 + (n - 28)] = bf16of(v);
                    } else if constexpr (MODE == 1) {
                        if (n < 576) {
                            const float e = bf2f(EXTI[((size_t)(b * 64 + n / 9)) * 1152 + kd * 9 + n % 9]);
                            yb[1792 + kd * 576 + n] = 0.5f * (v + e);
                        } else if (n == 576) yb[75520 + kd] = 0.5f * v;
                        else EXTO[((size_t)(b * 128 + kd)) * E1S + (n - 576)] = bf16of(v);
                    } else {
                        if (n < 1152) {
                            const float e = bf2f(panel[(n / 9 - row_lo) * 296 + ml * 9 + n % 9 + 1]);
                            yb[75648 + kd * 1152 + n] = v + e;
                        } else if (n == 1152) yb[370560 + kd] = v;
                    }
                }
            }
        }
    }
}

extern "C" void kernel_launch(void* const* d_in, const int* in_sizes, int n_in,
                              void* d_out, int out_size, void* d_ws, size_t ws_size,
                              hipStream_t stream)
{
    const float* x  = (const float*)d_in[0];
    const float* W0 = (const float*)d_in[1];
    const float* b0 = (const float*)d_in[2];
    const float* W1 = (const float*)d_in[3];
    const float* b1 = (const float*)d_in[4];
    const float* W2 = (const float*)d_in[5];
    const float* b2 = (const float*)d_in[6];
    float* y = (float*)d_out;

    // ws (bf16): XB | WT0 | WT1 | WT2 | EXT0[128*64*1152] | EXT1[128*128*2308]
    unsigned short* XB   = (unsigned short*)d_ws;
    unsigned short* WT0  = XB   + (size_t)128 * 448 * 512;
    unsigned short* WT1  = WT0  + (size_t)1180 * 512;
    unsigned short* WT2  = WT1  + (size_t)2881 * 512;
    unsigned short* EXT0 = WT2  + (size_t)1153 * 512;
    unsigned short* EXT1 = EXT0 + (size_t)128 * 64 * 1152;

    cvt_x<<<dim3(14336), 256, 0, stream>>>(x, XB);
    cvt_w<1180><<<dim3((1180 * 64 + 255) / 256), 256, 0, stream>>>(W0, WT0);
    cvt_w<2881><<<dim3((2881 * 64 + 255) / 256), 256, 0, stream>>>(W1, WT1);
    cvt_w<1153><<<dim3((1153 * 64 + 255) / 256), 256, 0, stream>>>(W2, WT2);

    // grids: (M/128) * ceil(N/256)  [R14 bug: MODE1/2 used half the m-tiles]
    gemm_big<0><<<dim3(64 * 5),   512, 0, stream>>>(XB, WT0, b0, y, nullptr, EXT0);
    gemm_big<1><<<dim3(128 * 12), 512, 0, stream>>>(XB, WT1, b1, y, EXT0, EXT1);
    gemm_big<2><<<dim3(256 * 5),  512, 0, stream>>>(XB, WT2, b2, y, EXT1, nullptr);
}

// Round 17
// 292.835 us; speedup vs baseline: 4.2314x; 4.2314x over previous
//
#include <hip/hip_runtime.h>
#include <cstdint>

typedef short short8 __attribute__((ext_vector_type(8)));
typedef float f32x4 __attribute__((ext_vector_type(4)));

#define LDS_AS3(p) ((__attribute__((address_space(3))) unsigned*)(p))
#define GLB_AS1(p) ((const __attribute__((address_space(1))) unsigned*)(p))

// fp32 -> bf16 (round-to-nearest-even), two packed into a u32
__device__ inline unsigned bfpack(float a, float b) {
    union { float f; unsigned u; } ua, ub;
    ua.f = a; ub.f = b;
    unsigned lo = (ua.u + 0x7FFFu + ((ua.u >> 16) & 1u)) >> 16;
    unsigned hi = (ub.u + 0x7FFFu + ((ub.u >> 16) & 1u)) & 0xFFFF0000u;
    return lo | hi;
}
__device__ inline unsigned short bf16of(float a) { return (unsigned short)bfpack(a, 0.0f); }
__device__ inline float bf2f(unsigned short s) {
    union { unsigned u; float f; } x; x.u = (unsigned)s << 16; return x.f;
}

constexpr int E1S = 2308;   // EXT1 row stride (shorts); col = n-576 (8B-aligned runs)

// ---------------- prepass: convert X to bf16 (same [.,448,512] layout) ------
__global__ __launch_bounds__(256)
void cvt_x(const float* __restrict__ X, unsigned short* __restrict__ XB)
{
    const int g = blockIdx.x * 256 + threadIdx.x;
    const float4 v0 = *(const float4*)(X + (size_t)g * 8);
    const float4 v1 = *(const float4*)(X + (size_t)g * 8 + 4);
    uint4 u;
    u.x = bfpack(v0.x, v0.y); u.y = bfpack(v0.z, v0.w);
    u.z = bfpack(v1.x, v1.y); u.w = bfpack(v1.z, v1.w);
    *(uint4*)(XB + (size_t)g * 8) = u;
}

// ------------- prepass: convert + transpose W[512][N] -> WT[N][512] bf16 ----
template <int N>
__global__ __launch_bounds__(256)
void cvt_w(const float* __restrict__ W, unsigned short* __restrict__ WT)
{
    const int g = blockIdx.x * 256 + threadIdx.x;
    if (g >= N * 64) return;
    const int n = g % N, d8 = g / N;
    const float* p = W + (size_t)d8 * 8 * N + n;
    uint4 u;
    u.x = bfpack(p[0],             p[(size_t)N]);
    u.y = bfpack(p[2 * (size_t)N], p[3 * (size_t)N]);
    u.z = bfpack(p[4 * (size_t)N], p[5 * (size_t)N]);
    u.w = bfpack(p[6 * (size_t)N], p[7 * (size_t)N]);
    *(uint4*)(WT + (size_t)n * 512 + d8 * 8) = u;
}

// ---- 128x256 GEMM, 512 thr (8 waves 2Mx4N), BK=32 dbuf, 2 blocks/CU --------
// R15 BUG FIX (rule #20): the epilogue pass loop is now FULLY UNROLLED so all
// acc[] indices are compile-time constants. R15's `acc[(h&1)*2+mi2]` with a
// runtime h forced the whole accumulator array into scratch (VGPR_Count=40,
// 4.5GB scratch traffic, MODE2 dispatch 1070us, MfmaUtil 1.6%).
template <int MODE>
__global__ __launch_bounds__(512, 4)
void gemm_big(const unsigned short* __restrict__ XB,
              const unsigned short* __restrict__ WT,
              const float* __restrict__ BIAS, float* __restrict__ Y,
              const unsigned short* __restrict__ EXTI,
              unsigned short* __restrict__ EXTO)
{
    constexpr int K_L  = (MODE == 0) ? 64 : (MODE == 1) ? 128 : 256;
    constexpr int LOGK = (MODE == 0) ? 6  : (MODE == 1) ? 7   : 8;
    constexpr int N    = (MODE == 0) ? 1180 : (MODE == 1) ? 2881 : 1153;
    constexpr int XOFF = (MODE == 0) ? 0 : (MODE == 1) ? 64 : 192;
    constexpr int NT   = (N + 255) / 256;
    constexpr int RPP   = (MODE == 2) ? 32 : 64;      // epilogue rows/pass
    constexpr int NPASS = 128 / RPP;
    constexpr int RPW   = RPP / 8;
    constexpr int SMEM  = (MODE == 2) ? 51200 : 66560; // max(K-loop 48K, epi)

    __shared__ __align__(16) char smem[SMEM];
    unsigned short* lAp = (unsigned short*)smem;      // [2][128*32] = 16KB
    unsigned short* lBp = lAp + 8192;                  // [2][256*32] = 32KB

    const int t    = threadIdx.x;            // 0..511
    const int lane = t & 63;
    const int wv   = t >> 6;                 // 0..7
    const int wr   = wv >> 2;                // m half 0..1
    const int wc   = wv & 3;                 // n quarter 0..3
    const int kq   = lane >> 4;
    const int lr16 = lane & 15;

    // bijective XCD-chunk swizzle (grids divisible by 8); N-minor order
    const int cpx = (int)gridDim.x >> 3;
    const int wg  = (blockIdx.x & 7) * cpx + (blockIdx.x >> 3);
    const int nt  = wg % NT;
    const int mt  = wg / NT;
    const int m0  = mt * 128;
    const int n0  = nt * 256;

    // stage one BK=32 tile: A 512 chunks + B 1024 chunks, 3 gload_lds/thread.
    // physical slot p holds logical k-slot p^((row>>1)&3) (proven R1 swizzle).
    auto stage = [&](int buf, int kt) {
        {   // A: 128 rows x 4 slots
            const int c   = t;
            const int row = c >> 2, p = c & 3, l = p ^ ((row >> 1) & 3);
            const int m   = m0 + row;
            const int b   = m >> LOGK, kd = m & (K_L - 1);
            const unsigned short* gp =
                XB + ((size_t)(b * 448 + XOFF + kd) << 9) + kt * 32 + l * 8;
            __builtin_amdgcn_global_load_lds(GLB_AS1(gp),
                LDS_AS3(lAp + buf * 4096 + c * 8), 16, 0, 0);
        }
        #pragma unroll
        for (int i = 0; i < 2; ++i) {   // B: 256 rows x 4 slots
            const int c   = i * 512 + t;
            const int row = c >> 2, p = c & 3, l = p ^ ((row >> 1) & 3);
            int gc = n0 + row; if (gc > N - 1) gc = N - 1;
            const unsigned short* gp = WT + (size_t)gc * 512 + kt * 32 + l * 8;
            __builtin_amdgcn_global_load_lds(GLB_AS1(gp),
                LDS_AS3(lBp + buf * 8192 + c * 8), 16, 0, 0);
        }
    };

    f32x4 acc[4][4] = {};

    // ---- K loop: 16 tiles of 32 --------------------------------------------
    stage(0, 0);
    __syncthreads();
    #pragma unroll 1
    for (int kt = 0; kt < 16; ++kt) {
        const int buf = kt & 1;
        if (kt < 15) stage(buf ^ 1, kt + 1);
        short8 af[4], bf[4];
        #pragma unroll
        for (int mi = 0; mi < 4; ++mi) {
            const int row = wr * 64 + mi * 16 + lr16;
            af[mi] = *(const short8*)(lAp + buf * 4096 + row * 32 + ((kq ^ ((row >> 1) & 3)) * 8));
        }
        #pragma unroll
        for (int ni = 0; ni < 4; ++ni) {
            const int row = wc * 64 + ni * 16 + lr16;
            bf[ni] = *(const short8*)(lBp + buf * 8192 + row * 32 + ((kq ^ ((row >> 1) & 3)) * 8));
        }
        __builtin_amdgcn_s_setprio(1);
        #pragma unroll
        for (int mi = 0; mi < 4; ++mi)
            #pragma unroll
            for (int ni = 0; ni < 4; ++ni)
                acc[mi][ni] = __builtin_amdgcn_mfma_f32_16x16x32_bf16(
                    af[mi], bf[ni], acc[mi][ni], 0, 0, 0);
        __builtin_amdgcn_s_setprio(0);
        __syncthreads();
    }

    // ================= epilogue (R12 structure, FULLY UNROLLED passes) =====
    float* LDSf = (float*)smem;                        // [RPP][260]
    unsigned short* panel = (unsigned short*)(smem + 33280);  // MODE2 only

    const int cls = (MODE == 0) ? ((n0 == 0 || n0 + 255 >= N) ? 2 : 1)
                  : (MODE == 1) ? ((n0 + 255 < 576) ? 0 : (n0 <= 576) ? 2
                                   : (n0 + 255 < N) ? 1 : 2)
                  :               ((n0 + 255 < 1152) ? 0 : 2);

    int row_lo = 0;
    #pragma unroll            // FULL unroll: all acc[] indices compile-time
    for (int h = 0; h < NPASS; ++h) {
        if (h) __syncthreads();
        if constexpr (MODE != 2) {
            if (wr == h) {
                #pragma unroll
                for (int mi = 0; mi < 4; ++mi)
                    #pragma unroll
                    for (int ni = 0; ni < 4; ++ni)
                        #pragma unroll
                        for (int r = 0; r < 4; ++r)
                            LDSf[(mi * 16 + kq * 4 + r) * 260 + wc * 64 + ni * 16 + lr16]
                                = acc[mi][ni][r];
            }
        } else {
            if (wr == (h >> 1)) {
                #pragma unroll
                for (int mi2 = 0; mi2 < 2; ++mi2)
                    #pragma unroll
                    for (int ni = 0; ni < 4; ++ni)
                        #pragma unroll
                        for (int r = 0; r < 4; ++r)
                            LDSf[(mi2 * 16 + kq * 4 + r) * 260 + wc * 64 + ni * 16 + lr16]
                                = acc[(h & 1) * 2 + mi2][ni][r];
            }
            // ---- load E1 panel (coalesced); kd range = (mt&1)*128+h*32 ..+32
            row_lo = n0 / 9;
            const int ntop  = (n0 + 256 <= 1152) ? (n0 + 255) : 1151;
            const int nrows = ntop / 9 - row_lo + 1;
            const int col0  = (mt & 1) * 1152 + h * 288;
            const int bB    = mt >> 1;
            for (int t2 = t; t2 < nrows * 73; t2 += 512) {
                const int rr2 = t2 / 73, cc = t2 % 73;
                const uint2 v = *(const uint2*)(EXTI +
                    ((size_t)(bB * 128 + row_lo + rr2)) * E1S + col0 + cc * 4);
                *(uint2*)(panel + rr2 * 296 + cc * 4) = v;
            }
        }
        __syncthreads();

        #pragma unroll 1
        for (int rr = 0; rr < RPW; ++rr) {
            const int ml = wv * RPW + rr;
            const int m  = m0 + h * RPP + ml;
            const int b  = m >> LOGK;
            const int kd = m & (K_L - 1);
            const int nb = n0 + lane * 4;
            const float4 v4 = *(const float4*)&LDSf[ml * 260 + lane * 4];
            float* yb = Y + (size_t)b * 370816;

            if (cls == 0) {
                const float4 b4 = *(const float4*)(BIAS + nb);
                float e[4];
                if constexpr (MODE == 1) {
                    #pragma unroll
                    for (int i = 0; i < 4; ++i) {
                        const int n = nb + i;
                        e[i] = bf2f(EXTI[((size_t)(b * 64 + n / 9)) * 1152 + kd * 9 + n % 9]);
                    }
                    float4 o;
                    o.x = 0.5f * (v4.x + b4.x + e[0]); o.y = 0.5f * (v4.y + b4.y + e[1]);
                    o.z = 0.5f * (v4.z + b4.z + e[2]); o.w = 0.5f * (v4.w + b4.w + e[3]);
                    *(float4*)(yb + 1792 + kd * 576 + nb) = o;
                } else {
                    #pragma unroll
                    for (int i = 0; i < 4; ++i) {
                        const int n = nb + i;
                        e[i] = bf2f(panel[(n / 9 - row_lo) * 296 + ml * 9 + n % 9 + 1]);
                    }
                    float4 o;
                    o.x = v4.x + b4.x + e[0]; o.y = v4.y + b4.y + e[1];
                    o.z = v4.z + b4.z + e[2]; o.w = v4.w + b4.w + e[3];
                    *(float4*)(yb + 75648 + kd * 1152 + nb) = o;
                }
                if (MODE == 2 && n0 + 256 > 1152 && lane == 32)
                    yb[370560 + kd] = LDSf[ml * 260 + 128] + BIAS[1152];
            } else if (cls == 1) {
                const float4 b4 = *(const float4*)(BIAS + nb);
                uint2 u;
                u.x = bfpack(v4.x + b4.x, v4.y + b4.y);
                u.y = bfpack(v4.z + b4.z, v4.w + b4.w);
                if constexpr (MODE == 0)
                    *(uint2*)(EXTO + ((size_t)(b * 64 + kd)) * 1152 + (nb - 28)) = u;
                else
                    *(uint2*)(EXTO + ((size_t)(b * 128 + kd)) * E1S + (nb - 576)) = u;
            } else {
                #pragma unroll
                for (int i = 0; i < 4; ++i) {
                    const int n = nb + i;
                    if (n >= N) continue;
                    const float v = ((const float*)&v4)[i] + BIAS[n];
                    if constexpr (MODE == 0) {
                        if (n < 27)       yb[kd * 27 + n] = v;
                        else if (n == 27) yb[1728 + kd]   = v;
                        else EXTO[((size_t)(b * 64 + kd)) * 1152 + (n - 28)] = bf16of(v);
                    } else if constexpr (MODE == 1) {
                        if (n < 576) {
                            const float e = bf2f(EXTI[((size_t)(b * 64 + n / 9)) * 1152 + kd * 9 + n % 9]);
                            yb[1792 + kd * 576 + n] = 0.5f * (v + e);
                        } else if (n == 576) yb[75520 + kd] = 0.5f * v;
                        else EXTO[((size_t)(b * 128 + kd)) * E1S + (n - 576)] = bf16of(v);
                    } else {
                        if (n < 1152) {
                            const float e = bf2f(panel[(n / 9 - row_lo) * 296 + ml * 9 + n % 9 + 1]);
                            yb[75648 + kd * 1152 + n] = v + e;
                        } else if (n == 1152) yb[370560 + kd] = v;
                    }
                }
            }
        }
    }
}

extern "C" void kernel_launch(void* const* d_in, const int* in_sizes, int n_in,
                              void* d_out, int out_size, void* d_ws, size_t ws_size,
                              hipStream_t stream)
{
    const float* x  = (const float*)d_in[0];
    const float* W0 = (const float*)d_in[1];
    const float* b0 = (const float*)d_in[2];
    const float* W1 = (const float*)d_in[3];
    const float* b1 = (const float*)d_in[4];
    const float* W2 = (const float*)d_in[5];
    const float* b2 = (const float*)d_in[6];
    float* y = (float*)d_out;

    // ws (bf16): XB | WT0 | WT1 | WT2 | EXT0[128*64*1152] | EXT1[128*128*2308]
    unsigned short* XB   = (unsigned short*)d_ws;
    unsigned short* WT0  = XB   + (size_t)128 * 448 * 512;
    unsigned short* WT1  = WT0  + (size_t)1180 * 512;
    unsigned short* WT2  = WT1  + (size_t)2881 * 512;
    unsigned short* EXT0 = WT2  + (size_t)1153 * 512;
    unsigned short* EXT1 = EXT0 + (size_t)128 * 64 * 1152;

    cvt_x<<<dim3(14336), 256, 0, stream>>>(x, XB);
    cvt_w<1180><<<dim3((1180 * 64 + 255) / 256), 256, 0, stream>>>(W0, WT0);
    cvt_w<2881><<<dim3((2881 * 64 + 255) / 256), 256, 0, stream>>>(W1, WT1);
    cvt_w<1153><<<dim3((1153 * 64 + 255) / 256), 256, 0, stream>>>(W2, WT2);

    // grids: (M/128) * ceil(N/256); stream order = EXT dependency
    gemm_big<0><<<dim3(64 * 5),   512, 0, stream>>>(XB, WT0, b0, y, nullptr, EXT0);
    gemm_big<1><<<dim3(128 * 12), 512, 0, stream>>>(XB, WT1, b1, y, EXT0, EXT1);
    gemm_big<2><<<dim3(256 * 5),  512, 0, stream>>>(XB, WT2, b2, y, EXT1, nullptr);
}